// Round 1
// baseline (9.499 us; speedup 1.0000x reference)
//
#include <hip/hip_runtime.h>
#include <hip/hip_bf16.h>

// QuantumFeatureExtractor: circuit is RX(x[b,i]+theta[i]) on each wire i,
// starting from |0..0>, with NO entangling gates. State is a product state,
// so <Z_i> = cos(x[b,i] + theta[i]) exactly. Output is [B=16, N=20] f32.

#define QFE_B 16
#define QFE_N 20

__global__ void qfe_cos_kernel(const float* __restrict__ x,
                               const float* __restrict__ theta,
                               float* __restrict__ out) {
    int idx = blockIdx.x * blockDim.x + threadIdx.x;
    const int total = QFE_B * QFE_N;
    if (idx < total) {
        int i = idx % QFE_N;          // wire index
        out[idx] = cosf(x[idx] + theta[i]);
    }
}

extern "C" void kernel_launch(void* const* d_in, const int* in_sizes, int n_in,
                              void* d_out, int out_size, void* d_ws, size_t ws_size,
                              hipStream_t stream) {
    const float* x     = (const float*)d_in[0];   // [16, 20] f32
    const float* theta = (const float*)d_in[1];   // [20]     f32
    float* out = (float*)d_out;                   // [16, 20] f32

    // 320 elements: one block of 320 threads (multiple of 64).
    qfe_cos_kernel<<<1, QFE_B * QFE_N, 0, stream>>>(x, theta, out);
}